// Round 2
// baseline (5895.734 us; speedup 1.0000x reference)
//
#include <hip/hip_runtime.h>
#include <math.h>

// Problem constants: SEQ=256, B=32, NVOC=10000, NIN=NH=256, gates=4
#define SEQ   256
#define BATCH 32
#define NVOC  10000
#define NH    256
#define NG4   1024          // NH*4 gate columns
#define MTOT  8192          // SEQ*BATCH

// Generic K=256 f32 GEMM: C[M=8192][N] = A[8192][256] * B[256][N] + bias[N]
// AMODE 0: A rows gathered from embed_W via tokens; AMODE 1: A dense f32.
// BT false: B row-major [256][N]; BT true: B[k][n] = Bsrc[n*256+k] (dec_W is [NVOC][NH])
template<int AMODE, bool BT>
__global__ __launch_bounds__(256)
void gemm_k256(const float* __restrict__ Aptr, const int* __restrict__ tokens,
               const float* __restrict__ Bptr, const float* __restrict__ bias,
               float* __restrict__ Cptr, int N)
{
    __shared__ __align__(16) float As[32][68];   // [k][m], +4 pad: float4-aligned rows, no conflicts
    __shared__ __align__(16) float Bs[32][68];   // [k][n]
    __shared__ int rowTok[64];

    const int tid  = threadIdx.x;
    const int row0 = blockIdx.x * 64;
    const int col0 = blockIdx.y * 64;

    if (AMODE == 0) {
        if (tid < 64) rowTok[tid] = tokens[row0 + tid];
        __syncthreads();
    }

    float acc[4][4] = {};
    const int ty = tid >> 4, tx = tid & 15;    // 16x16 thread grid, 4x4 outputs each
    const int lr = tid >> 2, lq = tid & 3;     // loader: row 0..63, 8-elem segment 0..3

    for (int kb = 0; kb < 256; kb += 32) {
        // ---- global -> regs ----
        float av[8];
        {
            const int arow = (AMODE == 0) ? rowTok[lr] : (row0 + lr);
            const float* src = Aptr + (size_t)arow * 256 + kb + lq * 8;
            float4 v0 = *(const float4*)src;
            float4 v1 = *(const float4*)(src + 4);
            av[0]=v0.x; av[1]=v0.y; av[2]=v0.z; av[3]=v0.w;
            av[4]=v1.x; av[5]=v1.y; av[6]=v1.z; av[7]=v1.w;
        }
        float bv[8];
        if (!BT) {
            const int kk = tid >> 3, sg = tid & 7;   // 32 k-rows x 8 segments
            const float* src = Bptr + (size_t)(kb + kk) * N + col0 + sg * 8;
            float4 v0 = *(const float4*)src;
            float4 v1 = *(const float4*)(src + 4);
            bv[0]=v0.x; bv[1]=v0.y; bv[2]=v0.z; bv[3]=v0.w;
            bv[4]=v1.x; bv[5]=v1.y; bv[6]=v1.z; bv[7]=v1.w;
        } else {
            const int gcol = col0 + lr;
            if (gcol < N) {
                const float* src = Bptr + (size_t)gcol * 256 + kb + lq * 8;
                float4 v0 = *(const float4*)src;
                float4 v1 = *(const float4*)(src + 4);
                bv[0]=v0.x; bv[1]=v0.y; bv[2]=v0.z; bv[3]=v0.w;
                bv[4]=v1.x; bv[5]=v1.y; bv[6]=v1.z; bv[7]=v1.w;
            } else {
                #pragma unroll
                for (int j = 0; j < 8; j++) bv[j] = 0.f;
            }
        }

        __syncthreads();   // previous tile's LDS reads complete before overwrite
        #pragma unroll
        for (int j = 0; j < 8; j++) As[lq * 8 + j][lr] = av[j];
        if (!BT) {
            const int kk = tid >> 3, sg = tid & 7;
            #pragma unroll
            for (int j = 0; j < 8; j++) Bs[kk][sg * 8 + j] = bv[j];
        } else {
            #pragma unroll
            for (int j = 0; j < 8; j++) Bs[lq * 8 + j][lr] = bv[j];
        }
        __syncthreads();

        // ---- inner product ----
        #pragma unroll
        for (int kk = 0; kk < 32; kk++) {
            float4 af = *(const float4*)(&As[kk][ty * 4]);
            float4 bf = *(const float4*)(&Bs[kk][tx * 4]);
            float ar[4] = {af.x, af.y, af.z, af.w};
            float br[4] = {bf.x, bf.y, bf.z, bf.w};
            #pragma unroll
            for (int i = 0; i < 4; i++)
                #pragma unroll
                for (int j = 0; j < 4; j++)
                    acc[i][j] = fmaf(ar[i], br[j], acc[i][j]);
        }
    }

    // ---- epilogue: bias + store ----
    #pragma unroll
    for (int i = 0; i < 4; i++) {
        const int row = row0 + ty * 4 + i;     // M=8192 divisible by 64 -> always valid
        #pragma unroll
        for (int j = 0; j < 4; j++) {
            const int col = col0 + tx * 4 + j;
            if (col < N)
                Cptr[(size_t)row * N + col] = acc[i][j] + bias[col];
        }
    }
}

// LSTM recurrence, one workgroup per batch element (grid=32, block=1024).
// gx: [SEQ*B][1024] f32 (bias already included). Wh: f32 [h][k*4+g].
// hseq out: [SEQ*B][256] f32. h,c start at zero.
__global__ __launch_bounds__(1024)
void lstm_layer(const float* __restrict__ gx, const float* __restrict__ Wh,
                float* __restrict__ hseq)
{
    const int b = blockIdx.x;
    const int tid = threadIdx.x;          // gate column: k = tid>>2, g = tid&3
    __shared__ float hbuf[256];
    __shared__ float zbuf[1024];
    float c = 0.f;
    if (tid < 256) hbuf[tid] = 0.f;
    __syncthreads();

    const float* __restrict__ wcol = Wh + tid;  // stride 1024 over h

    for (int t = 0; t < SEQ; ++t) {
        float a0 = gx[((size_t)t * BATCH + b) * NG4 + tid];
        float a1 = 0.f, a2 = 0.f, a3 = 0.f;
        #pragma unroll 8
        for (int h = 0; h < 256; h += 4) {
            float h0 = hbuf[h + 0], h1 = hbuf[h + 1], h2 = hbuf[h + 2], h3 = hbuf[h + 3];
            a0 = fmaf(h0, wcol[(size_t)(h + 0) << 10], a0);
            a1 = fmaf(h1, wcol[(size_t)(h + 1) << 10], a1);
            a2 = fmaf(h2, wcol[(size_t)(h + 2) << 10], a2);
            a3 = fmaf(h3, wcol[(size_t)(h + 3) << 10], a3);
        }
        zbuf[tid] = (a0 + a1) + (a2 + a3);
        __syncthreads();                         // all hbuf reads + zbuf writes done
        if (tid < 256) {
            float zi = zbuf[tid * 4 + 0];
            float zf = zbuf[tid * 4 + 1];
            float zo = zbuf[tid * 4 + 2];
            float zg = zbuf[tid * 4 + 3];
            float ig = 1.f / (1.f + expf(-zi));
            float fg = 1.f / (1.f + expf(-zf));
            float og = 1.f / (1.f + expf(-zo));
            float gg = tanhf(zg);
            c = fmaf(fg, c, ig * gg);
            float hn = og * tanhf(c);
            hbuf[tid] = hn;                      // safe: all readers past barrier above
            hseq[((size_t)t * BATCH + b) * NH + tid] = hn;
        }
        __syncthreads();                         // hbuf updated before next step's reads
    }
}

// h1 = layer0 last hidden, h2 = layer1 last hidden -> appended to d_out (f32)
__global__ __launch_bounds__(256)
void copy_hlast(const float* __restrict__ h1seq, const float* __restrict__ h2seq,
                float* __restrict__ out)
{
    const int i = blockIdx.x * 256 + threadIdx.x;          // 0..8191 = b*256+k
    const size_t lastoff = (size_t)(SEQ - 1) * BATCH * NH; // 2088960
    out[(size_t)MTOT * NVOC + i]        = h1seq[lastoff + i];
    out[(size_t)MTOT * NVOC + 8192 + i] = h2seq[lastoff + i];
}

extern "C" void kernel_launch(void* const* d_in, const int* in_sizes, int n_in,
                              void* d_out, int out_size, void* d_ws, size_t ws_size,
                              hipStream_t stream)
{
    const int*   tokens = (const int*)d_in[0];
    const float* embed  = (const float*)d_in[1];
    const float* Wx0    = (const float*)d_in[2];
    const float* Wh0    = (const float*)d_in[3];
    const float* b0     = (const float*)d_in[4];
    const float* Wx1    = (const float*)d_in[5];
    const float* Wh1    = (const float*)d_in[6];
    const float* b1     = (const float*)d_in[7];
    const float* decW   = (const float*)d_in[8];
    const float* decb   = (const float*)d_in[9];

    float* out = (float*)d_out;

    // Scratch: gx[8192][1024] f32 (33.5 MB) lives in the FRONT of d_out (328 MB);
    // the decoder GEMM fully overwrites it at the end. d_ws holds h1seq/h2seq only.
    float* gx    = out;
    float* h1seq = (float*)d_ws;                 // 8,388,608 B
    float* h2seq = h1seq + (size_t)MTOT * NH;    // 8,388,608 B (total 16.8 MB of ws)

    // layer 0: gate inputs (embedding gather fused) then recurrence
    gemm_k256<0, false><<<dim3(128, 16), 256, 0, stream>>>(embed, tokens, Wx0, b0, gx, NG4);
    lstm_layer<<<32, 1024, 0, stream>>>(gx, Wh0, h1seq);

    // layer 1
    gemm_k256<1, false><<<dim3(128, 16), 256, 0, stream>>>(h1seq, nullptr, Wx1, b1, gx, NG4);
    lstm_layer<<<32, 1024, 0, stream>>>(gx, Wh1, h2seq);

    // decoder: [8192,256] @ dec_W^T[256,10000] + dec_b -> f32 d_out
    gemm_k256<1, true><<<dim3(128, 157), 256, 0, stream>>>(h2seq, nullptr, decW, decb, out, NVOC);

    // h1, h2 tails
    copy_hlast<<<32, 256, 0, stream>>>(h1seq, h2seq, out);
}